// Round 10
// baseline (158.065 us; speedup 1.0000x reference)
//
#include <hip/hip_runtime.h>
#include <math.h>

#define DD    128
#define DI    170
#define DIP   176            // padded i-dimension (zero pad cols 170..175)
#define ND4   32             // DD/4 d-chunks
#define ND4H  16             // half of ND4 (split-d)
#define NI4P  44             // padded i4 chunk count (chunk 42 half, 43 zero)
#define BB    4096
#define NNEG  5
#define ROWS  4
#define NBLK  (BB / ROWS)    // 1024 blocks -> 4 blocks/CU at 8 waves/SIMD
#define NTHR  512
#define NTASK (ROWS * (1 + NNEG))   // 24 gather tasks
#define SQRT_D 11.3137084989847603904f   // sqrt(128)

// workspace layout (floats)
#define WS_WHT 0                          // [32][176] float4
#define WS_WGT (ND4 * DIP * 4)            // 22528 floats
#define WS_WFT (2 * ND4 * DIP * 4)        // 45056 floats; [44][128] float4

__device__ __forceinline__ float wave_bcast_sum(float v) {
#pragma unroll
    for (int m = 1; m < 64; m <<= 1) v += __shfl_xor(v, m, 64);
    return v;
}

// Prep: per-call recompute of normalized+scale-folded TRANSPOSED weights into ws.
//  whT4[d4][i]  = W_hidden[i][4d4+c] * inv_h[i]*hidden_scale[i]*inv_f[i]
//  wgT4[d4][i]  = W_gate  [i][4d4+c] * inv_g[i]*gate_scale[i]*sqrt(D)
//  wfT4[i4][dd] = W_ff_out[dd][4i4+c]  (raw; col-norms folded via whT)
__global__ __launch_bounds__(256) void prep_kernel(
    const float* __restrict__ W_hidden,
    const float* __restrict__ W_gate,
    const float* __restrict__ W_ff_out,
    const float* __restrict__ hidden_scale,
    const float* __restrict__ gate_scale,
    float* __restrict__ ws,
    float* __restrict__ out)
{
    if (blockIdx.x == 0 && threadIdx.x == 0) out[0] = 0.0f;
    const int wave = threadIdx.x >> 6;
    const int lane = threadIdx.x & 63;
    const int t = blockIdx.x * 4 + wave;
    float* whT = ws + WS_WHT;
    float* wgT = ws + WS_WGT;
    float* wfT = ws + WS_WFT;

    if (t < DI) {
        const int v = t;
        // inverse norm of W_ff_out column v (128 entries, stride DI)
        float a = W_ff_out[(long)(2 * lane)     * DI + v];
        float b = W_ff_out[(long)(2 * lane + 1) * DI + v];
        float cf = wave_bcast_sum(a * a + b * b);
        // row norms of W_hidden / W_gate row v
        float2 ph = ((const float2*)(W_hidden + (long)v * DD))[lane];
        float2 pg = ((const float2*)(W_gate   + (long)v * DD))[lane];
        float sh = wave_bcast_sum(ph.x * ph.x + ph.y * ph.y);
        float sg = wave_bcast_sum(pg.x * pg.x + pg.y * pg.y);
        const float whs = rsqrtf(sh) * hidden_scale[v] * rsqrtf(cf);
        const float wgs = rsqrtf(sg) * gate_scale[v] * SQRT_D;
        // transposed write: lane holds d = 2*lane, 2*lane+1 -> d4 = lane>>1
        const int d4   = lane >> 1;
        const int half = lane & 1;                  // 0: comps {0,1}, 1: comps {2,3}
        float2* dh = (float2*)(whT + ((long)d4 * DIP + v) * 4 + half * 2);
        *dh = make_float2(ph.x * whs, ph.y * whs);
        float2* dg = (float2*)(wgT + ((long)d4 * DIP + v) * 4 + half * 2);
        *dg = make_float2(pg.x * wgs, pg.y * wgs);
    } else if (t < DI + NI4P) {
        const int i4 = t - DI;                      // 0..43
#pragma unroll
        for (int rr = 0; rr < 2; ++rr) {
            const int dd = rr * 64 + lane;
            float4 v4;
            if (i4 < 42) {   // rows are 8B-aligned (680B): use two float2 loads
                float2 lo = *(const float2*)(W_ff_out + (long)dd * DI + 4 * i4);
                float2 hi = *(const float2*)(W_ff_out + (long)dd * DI + 4 * i4 + 2);
                v4 = make_float4(lo.x, lo.y, hi.x, hi.y);
            } else if (i4 == 42) {  // i = 168,169 valid; 170,171 zero-pad
                float2 lo = *(const float2*)(W_ff_out + (long)dd * DI + 168);
                v4 = make_float4(lo.x, lo.y, 0.0f, 0.0f);
            } else {                // i4 == 43: all pad
                v4 = make_float4(0.0f, 0.0f, 0.0f, 0.0f);
            }
            *(float4*)(wfT + ((long)i4 * DD + dd) * 4) = v4;
        }
    } else if (t == DI + NI4P || t == DI + NI4P + 1) {
        // zero pad columns 170..175 of whT / wgT
        float* base = (t == DI + NI4P) ? whT : wgT;
        for (int idx = lane; idx < ND4 * 6; idx += 64) {
            const int d4 = idx / 6, c = idx % 6;
            *(float4*)(base + ((long)d4 * DIP + DI + c) * 4) =
                make_float4(0.0f, 0.0f, 0.0f, 0.0f);
        }
    }
}

__global__ __launch_bounds__(NTHR, 8) void main_kernel(
    const int*   __restrict__ input_ids,
    const int*   __restrict__ target_ids,
    const int*   __restrict__ neg_ids,
    const float* __restrict__ W_in,
    const float* __restrict__ W_out,
    const float* __restrict__ logit_scale,
    const float* __restrict__ ws,
    float* __restrict__ out)
{
    __shared__ __align__(16) float s_emb[ROWS][DD];    // 2 KB
    __shared__ __align__(16) float s_x[ROWS][DIP];     // 2.75 KB
    __shared__ __align__(16) float s_pp[8][ROWS][DD];  // 16 KB: 2b 8-slice partials
    __shared__ __align__(16) float s_xout[ROWS][DD];   // 2 KB
    __shared__ float s_part[DIP][9];                   // split-d partials, stride 9
    __shared__ float s_pinv[NTASK];                    // rsqrt(|W_out row|^2)
    __shared__ float s_psc[NTASK];                     // logit_scale[id]
    __shared__ int   s_ids[NTASK];
    __shared__ float s_red[8];

    const int tid  = threadIdx.x;
    const int wave = tid >> 6;
    const int lane = tid & 63;
    const int b0   = blockIdx.x * ROWS;

    const float4* whT4 = (const float4*)(ws + WS_WHT);  // [32][176]
    const float4* wgT4 = (const float4*)(ws + WS_WGT);
    const float4* wfT4 = (const float4*)(ws + WS_WFT);  // [44][128]

    // ---- Phase 1: gather + l2-normalize input embeddings; wave w -> row w ----
    if (wave < ROWS) {
        const int id = input_ids[b0 + wave];
        float2 p = ((const float2*)(W_in + (long)id * DD))[lane];
        float s  = wave_bcast_sum(p.x * p.x + p.y * p.y);
        float inv = rsqrtf(s);
        s_emb[wave][2 * lane]     = p.x * inv;
        s_emb[wave][2 * lane + 1] = p.y * inv;
    }
    __syncthreads();

    // ---- Phase 2 (waves 0-2, 4-6): FUSED h+g per thread, split-d across
    //      groups: G_A (tid<176) d4 0..15, G_B (256..431) d4 16..31.
    //      CONCURRENTLY, waves 3 and 7 (idle in P2) run phase-3's gather
    //      half: W_out row norms + logit_scale + ids into LDS. Their vmcnt
    //      queues are otherwise unused, so P2 loads are not delayed; the
    //      gathered rows stay L2-hot for phase 3's re-read. ----
    const bool gA = (tid < DIP);
    const bool gB = (tid >= 256 && tid < 256 + DIP);
    const int i = gA ? tid : (gB ? tid - 256 : -1);
    float ah[ROWS], ag[ROWS];
#pragma unroll
    for (int r = 0; r < ROWS; ++r) { ah[r] = 0.0f; ag[r] = 0.0f; }

    if (i >= 0) {
        const int d4lo = gA ? 0 : ND4H;
#pragma unroll 4
        for (int k = 0; k < ND4H; ++k) {
            const int d4 = d4lo + k;
            float4 h4 = whT4[d4 * DIP + i];      // lane-consecutive: coalesced
            float4 g4 = wgT4[d4 * DIP + i];
#pragma unroll
            for (int r = 0; r < ROWS; ++r) {
                float4 e4 = ((const float4*)s_emb[r])[d4];   // uniform: broadcast
                ah[r] += e4.x * h4.x + e4.y * h4.y + e4.z * h4.z + e4.w * h4.w;
                ag[r] += e4.x * g4.x + e4.y * g4.y + e4.z * g4.z + e4.w * g4.w;
            }
        }
    } else if (wave == 3 || wave == 7) {
        const int tb = (wave == 3) ? 0 : 12;
#pragma unroll 6
        for (int k = 0; k < 12; ++k) {
            const int t  = tb + k;
            const int r  = t / (1 + NNEG);
            const int jj = t % (1 + NNEG);
            const int bidx = b0 + r;
            const int id = (jj == 0) ? target_ids[bidx]
                                     : neg_ids[bidx * NNEG + jj - 1];
            const float* wrow = W_out + (long)id * DD;
            float w0 = wrow[lane], w1 = wrow[64 + lane];
            float ss = w0 * w0 + w1 * w1;
#pragma unroll
            for (int m = 1; m < 64; m <<= 1) ss += __shfl_xor(ss, m, 64);
            if (lane == 0) {
                s_pinv[t] = rsqrtf(ss);
                s_psc[t]  = logit_scale[id];
                s_ids[t]  = id;
            }
        }
    }
    if (gB) {
#pragma unroll
        for (int r = 0; r < ROWS; ++r) {
            s_part[i][r]        = ah[r];
            s_part[i][ROWS + r] = ag[r];
        }
    }
    __syncthreads();

    if (gA) {
#pragma unroll
        for (int r = 0; r < ROWS; ++r) {
            float h = ah[r] + s_part[i][r];           // (d4<16) + (d4>=16)
            float g = ag[r] + s_part[i][ROWS + r];
            float x = (g / (1.0f + __expf(-g))) * h;  // silu(g) * h
            s_x[r][i] = x;                            // pad cols: 0
        }
    }
    __syncthreads();

    // ---- Phase 2b: 8-way i4 slicing (wave = slice), dd-coarsen 2x
    //      (lane owns dd=lane and dd=lane+64). wfT streamed once/block. ----
    {
        const int i4lo = (wave < 4) ? 6 * wave : 24 + 5 * (wave - 4);
        const int i4n  = (wave < 4) ? 6 : 5;
        float acc0[ROWS], acc1[ROWS];
#pragma unroll
        for (int r = 0; r < ROWS; ++r) { acc0[r] = 0.0f; acc1[r] = 0.0f; }
        for (int k = 0; k < i4n; ++k) {
            const int i4 = i4lo + k;
            float4 wa = wfT4[i4 * DD + lane];         // coalesced
            float4 wb = wfT4[i4 * DD + 64 + lane];
#pragma unroll
            for (int r = 0; r < ROWS; ++r) {
                float4 x4 = ((const float4*)s_x[r])[i4];     // uniform: broadcast
                acc0[r] += wa.x * x4.x + wa.y * x4.y + wa.z * x4.z + wa.w * x4.w;
                acc1[r] += wb.x * x4.x + wb.y * x4.y + wb.z * x4.z + wb.w * x4.w;
            }
        }
#pragma unroll
        for (int r = 0; r < ROWS; ++r) {
            s_pp[wave][r][lane]      = acc0[r];
            s_pp[wave][r][64 + lane] = acc1[r];
        }
    }
    __syncthreads();

    // ---- materialize xout: fixed 8-term fold (deterministic) ----
    {
        const int dd = tid & 127;
        const int r  = tid >> 7;                  // 0..3
        float v = s_pp[0][r][dd];
#pragma unroll
        for (int q = 1; q < 8; ++q) v += s_pp[q][r][dd];
        s_xout[r][dd] = v;
    }
    __syncthreads();

    // ---- Phase 3: logits. Row norm + scale + id precomputed by waves 3/7;
    //      W_out rows re-read L2-hot; single (dot) butterfly remains. ----
    float wacc = 0.0f;
#pragma unroll
    for (int k = 0; k < 3; ++k) {
        const int t  = wave + 8 * k;
        const int r  = t / (1 + NNEG);
        const int jj = t % (1 + NNEG);
        const int id = s_ids[t];
        const float* wrow = W_out + (long)id * DD;
        float w0 = wrow[lane], w1 = wrow[64 + lane];
        float x0 = s_xout[r][lane], x1 = s_xout[r][64 + lane];
        float dot = w0 * x0 + w1 * x1;
#pragma unroll
        for (int m = 1; m < 64; m <<= 1) dot += __shfl_xor(dot, m, 64);
        const float logit = dot * s_pinv[t] * s_psc[t] * SQRT_D;
        const float z  = (jj == 0) ? logit : -logit;
        const float ls = fminf(z, 0.0f) - log1pf(__expf(-fabsf(z)));   // stable log_sigmoid
        wacc += (jj == 0) ? ls * (1.0f / BB) : ls * (1.0f / (BB * NNEG));
    }
    if (lane == 0) s_red[wave] = wacc;
    __syncthreads();
    if (tid == 0) {
        float tot = s_red[0] + s_red[1] + s_red[2] + s_red[3]
                  + s_red[4] + s_red[5] + s_red[6] + s_red[7];
        atomicAdd(out, -tot);
    }
}

extern "C" void kernel_launch(void* const* d_in, const int* in_sizes, int n_in,
                              void* d_out, int out_size, void* d_ws, size_t ws_size,
                              hipStream_t stream) {
    (void)in_sizes; (void)n_in; (void)out_size; (void)ws_size;
    const int*   input_ids    = (const int*)  d_in[0];
    const int*   target_ids   = (const int*)  d_in[1];
    const int*   neg_ids      = (const int*)  d_in[2];
    const float* W_in         = (const float*)d_in[3];
    const float* W_out        = (const float*)d_in[4];
    const float* W_hidden     = (const float*)d_in[5];
    const float* W_gate       = (const float*)d_in[6];
    const float* W_ff_out     = (const float*)d_in[7];
    const float* hidden_scale = (const float*)d_in[8];
    const float* gate_scale   = (const float*)d_in[9];
    const float* logit_scale  = (const float*)d_in[10];
    float* out = (float*)d_out;
    float* ws  = (float*)d_ws;     // needs 270 KB

    prep_kernel<<<54, 256, 0, stream>>>(W_hidden, W_gate, W_ff_out,
                                        hidden_scale, gate_scale, ws, out);
    main_kernel<<<NBLK, NTHR, 0, stream>>>(input_ids, target_ids, neg_ids,
                                           W_in, W_out, logit_scale, ws, out);
}

// Round 11
// 148.530 us; speedup vs baseline: 1.0642x; 1.0642x over previous
//
#include <hip/hip_runtime.h>
#include <math.h>

#define DD    128
#define DI    170
#define DIP   176            // padded i-dimension (zero pad cols 170..175)
#define ND4   32             // DD/4 d-chunks
#define ND4H  16             // half of ND4 (split-d)
#define NI4P  44             // padded i4 chunk count (chunk 42 half, 43 zero)
#define BB    4096
#define NNEG  5
#define ROWS  8
#define NBLK  (BB / ROWS)    // 512 blocks -> ONE cohort: 2 blocks/CU resident
#define NTHR  512
#define NTASK (ROWS * (1 + NNEG))   // 48 gather tasks
#define XOP   132            // padded s_xout row stride (floats)
#define SQRT_D 11.3137084989847603904f   // sqrt(128)

// workspace layout (floats)
#define WS_WHT 0                          // [32][176] float4
#define WS_WGT (ND4 * DIP * 4)            // 22528 floats
#define WS_WFT (2 * ND4 * DIP * 4)        // 45056 floats; [44][128] float4

__device__ __forceinline__ float wave_bcast_sum(float v) {
#pragma unroll
    for (int m = 1; m < 64; m <<= 1) v += __shfl_xor(v, m, 64);
    return v;
}

// Prep: per-call recompute of normalized+scale-folded TRANSPOSED weights into ws.
//  whT4[d4][i]  = W_hidden[i][4d4+c] * inv_h[i]*hidden_scale[i]*inv_f[i]
//  wgT4[d4][i]  = W_gate  [i][4d4+c] * inv_g[i]*gate_scale[i]*sqrt(D)
//  wfT4[i4][dd] = W_ff_out[dd][4i4+c]  (raw; col-norms folded via whT)
__global__ __launch_bounds__(256) void prep_kernel(
    const float* __restrict__ W_hidden,
    const float* __restrict__ W_gate,
    const float* __restrict__ W_ff_out,
    const float* __restrict__ hidden_scale,
    const float* __restrict__ gate_scale,
    float* __restrict__ ws,
    float* __restrict__ out)
{
    if (blockIdx.x == 0 && threadIdx.x == 0) out[0] = 0.0f;
    const int wave = threadIdx.x >> 6;
    const int lane = threadIdx.x & 63;
    const int t = blockIdx.x * 4 + wave;
    float* whT = ws + WS_WHT;
    float* wgT = ws + WS_WGT;
    float* wfT = ws + WS_WFT;

    if (t < DI) {
        const int v = t;
        // inverse norm of W_ff_out column v (128 entries, stride DI)
        float a = W_ff_out[(long)(2 * lane)     * DI + v];
        float b = W_ff_out[(long)(2 * lane + 1) * DI + v];
        float cf = wave_bcast_sum(a * a + b * b);
        // row norms of W_hidden / W_gate row v
        float2 ph = ((const float2*)(W_hidden + (long)v * DD))[lane];
        float2 pg = ((const float2*)(W_gate   + (long)v * DD))[lane];
        float sh = wave_bcast_sum(ph.x * ph.x + ph.y * ph.y);
        float sg = wave_bcast_sum(pg.x * pg.x + pg.y * pg.y);
        const float whs = rsqrtf(sh) * hidden_scale[v] * rsqrtf(cf);
        const float wgs = rsqrtf(sg) * gate_scale[v] * SQRT_D;
        // transposed write: lane holds d = 2*lane, 2*lane+1 -> d4 = lane>>1
        const int d4   = lane >> 1;
        const int half = lane & 1;                  // 0: comps {0,1}, 1: comps {2,3}
        float2* dh = (float2*)(whT + ((long)d4 * DIP + v) * 4 + half * 2);
        *dh = make_float2(ph.x * whs, ph.y * whs);
        float2* dg = (float2*)(wgT + ((long)d4 * DIP + v) * 4 + half * 2);
        *dg = make_float2(pg.x * wgs, pg.y * wgs);
    } else if (t < DI + NI4P) {
        const int i4 = t - DI;                      // 0..43
#pragma unroll
        for (int rr = 0; rr < 2; ++rr) {
            const int dd = rr * 64 + lane;
            float4 v4;
            if (i4 < 42) {   // rows are 8B-aligned (680B): use two float2 loads
                float2 lo = *(const float2*)(W_ff_out + (long)dd * DI + 4 * i4);
                float2 hi = *(const float2*)(W_ff_out + (long)dd * DI + 4 * i4 + 2);
                v4 = make_float4(lo.x, lo.y, hi.x, hi.y);
            } else if (i4 == 42) {  // i = 168,169 valid; 170,171 zero-pad
                float2 lo = *(const float2*)(W_ff_out + (long)dd * DI + 168);
                v4 = make_float4(lo.x, lo.y, 0.0f, 0.0f);
            } else {                // i4 == 43: all pad
                v4 = make_float4(0.0f, 0.0f, 0.0f, 0.0f);
            }
            *(float4*)(wfT + ((long)i4 * DD + dd) * 4) = v4;
        }
    } else if (t == DI + NI4P || t == DI + NI4P + 1) {
        // zero pad columns 170..175 of whT / wgT
        float* base = (t == DI + NI4P) ? whT : wgT;
        for (int idx = lane; idx < ND4 * 6; idx += 64) {
            const int d4 = idx / 6, c = idx % 6;
            *(float4*)(base + ((long)d4 * DIP + DI + c) * 4) =
                make_float4(0.0f, 0.0f, 0.0f, 0.0f);
        }
    }
}

__global__ __launch_bounds__(NTHR, 4) void main_kernel(
    const int*   __restrict__ input_ids,
    const int*   __restrict__ target_ids,
    const int*   __restrict__ neg_ids,
    const float* __restrict__ W_in,
    const float* __restrict__ W_out,
    const float* __restrict__ logit_scale,
    const float* __restrict__ ws,
    float* __restrict__ out)
{
    __shared__ __align__(16) float s_emb[ROWS][DD];    // 4 KB
    __shared__ __align__(16) float s_x[ROWS][DIP];     // 5.5 KB
    __shared__ __align__(16) float s_pp[8][ROWS][DD];  // 32 KB: 2b 8-slice partials
    __shared__ __align__(16) float s_xout[ROWS][XOP];  // 4.125 KB (132-pad)
    __shared__ float s_part[DIP][2 * ROWS + 1];        // [176][17]: split-d partials
    __shared__ float s_dp[NTASK][9];                   // P3 dot partials
    __shared__ float s_sp[NTASK][9];                   // P3 |w|^2 partials
    __shared__ float s_psc[NTASK];                     // logit_scale[id]
    __shared__ float s_ls[NTASK];                      // weighted log-sigmoid

    const int tid  = threadIdx.x;
    const int wave = tid >> 6;
    const int lane = tid & 63;
    const int b0   = blockIdx.x * ROWS;

    const float4* whT4 = (const float4*)(ws + WS_WHT);  // [32][176]
    const float4* wgT4 = (const float4*)(ws + WS_WGT);
    const float4* wfT4 = (const float4*)(ws + WS_WFT);  // [44][128]

    // ---- Phase 1: gather + l2-normalize input embeddings; wave w -> row w.
    //      All 8 waves issue their gathers in parallel: one latency round. ----
    {
        const int id = input_ids[b0 + wave];
        float2 p = ((const float2*)(W_in + (long)id * DD))[lane];
        float s  = wave_bcast_sum(p.x * p.x + p.y * p.y);
        float inv = rsqrtf(s);
        s_emb[wave][2 * lane]     = p.x * inv;
        s_emb[wave][2 * lane + 1] = p.y * inv;
    }
    __syncthreads();

    // ---- Phase 2: FUSED h+g per thread (1 e4 broadcast feeds 16 FMAs),
    //      split-d: G_A (tid<176) d4 0..15, G_B (256..431) d4 16..31.
    //      Partials merged in fixed (A_total + B_total) order. ----
    const bool gA = (tid < DIP);
    const bool gB = (tid >= 256 && tid < 256 + DIP);
    const int i = gA ? tid : (gB ? tid - 256 : -1);
    float ah[ROWS], ag[ROWS];
#pragma unroll
    for (int r = 0; r < ROWS; ++r) { ah[r] = 0.0f; ag[r] = 0.0f; }

    if (i >= 0) {
        const int d4lo = gA ? 0 : ND4H;
#pragma unroll 4
        for (int k = 0; k < ND4H; ++k) {
            const int d4 = d4lo + k;
            float4 h4 = whT4[d4 * DIP + i];      // lane-consecutive: coalesced
            float4 g4 = wgT4[d4 * DIP + i];
#pragma unroll
            for (int r = 0; r < ROWS; ++r) {
                float4 e4 = ((const float4*)s_emb[r])[d4];   // uniform: broadcast
                ah[r] += e4.x * h4.x + e4.y * h4.y + e4.z * h4.z + e4.w * h4.w;
                ag[r] += e4.x * g4.x + e4.y * g4.y + e4.z * g4.z + e4.w * g4.w;
            }
        }
    }
    if (gB) {
#pragma unroll
        for (int r = 0; r < ROWS; ++r) {
            s_part[i][r]        = ah[r];
            s_part[i][ROWS + r] = ag[r];
        }
    }
    __syncthreads();

    if (gA) {
#pragma unroll
        for (int r = 0; r < ROWS; ++r) {
            float h = ah[r] + s_part[i][r];           // (d4<16) + (d4>=16)
            float g = ag[r] + s_part[i][ROWS + r];
            float x = (g / (1.0f + __expf(-g))) * h;  // silu(g) * h
            s_x[r][i] = x;                            // pad cols: 0
        }
    }
    __syncthreads();

    // ---- Phase 2b: 8-way i4 slicing (wave = slice), dd-coarsen 2x
    //      (lane owns dd=lane and dd=lane+64). wfT streamed once/block. ----
    {
        const int i4lo = (wave < 4) ? 6 * wave : 24 + 5 * (wave - 4);
        const int i4n  = (wave < 4) ? 6 : 5;
        float acc0[ROWS], acc1[ROWS];
#pragma unroll
        for (int r = 0; r < ROWS; ++r) { acc0[r] = 0.0f; acc1[r] = 0.0f; }
        for (int k = 0; k < i4n; ++k) {
            const int i4 = i4lo + k;
            float4 wa = wfT4[i4 * DD + lane];         // coalesced
            float4 wb = wfT4[i4 * DD + 64 + lane];
#pragma unroll
            for (int r = 0; r < ROWS; ++r) {
                float4 x4 = ((const float4*)s_x[r])[i4];     // uniform: broadcast
                acc0[r] += wa.x * x4.x + wa.y * x4.y + wa.z * x4.z + wa.w * x4.w;
                acc1[r] += wb.x * x4.x + wb.y * x4.y + wb.z * x4.z + wb.w * x4.w;
            }
        }
#pragma unroll
        for (int r = 0; r < ROWS; ++r) {
            s_pp[wave][r][lane]      = acc0[r];
            s_pp[wave][r][64 + lane] = acc1[r];
        }
    }
    __syncthreads();

    // ---- materialize xout: fixed 8-term fold (deterministic) ----
    {
        const int dd = tid & 127;
        const int r0 = tid >> 7;                  // 0..3; rows r0, r0+4
#pragma unroll
        for (int rr = 0; rr < 2; ++rr) {
            const int r = r0 + 4 * rr;
            float v = s_pp[0][r][dd];
#pragma unroll
            for (int q = 1; q < 8; ++q) v += s_pp[q][r][dd];
            s_xout[r][dd] = v;
        }
    }
    __syncthreads();

    // ---- Phase 3a: DATA-PARALLEL gathered logits. 8 threads per task,
    //      thread c owns float4 chunks j = c + 8*k2 (bank-spread in LDS,
    //      contiguous 128B rounds in global). All 48 W_out rows issued in
    //      parallel: ONE gather-latency round for the whole block. ----
    if (tid < NTASK * 8) {
        const int t  = tid >> 3;                  // 0..47
        const int c  = tid & 7;                   // 0..7
        const int r  = t / (1 + NNEG);
        const int jj = t % (1 + NNEG);
        const int bidx = b0 + r;
        const int id = (jj == 0) ? target_ids[bidx] : neg_ids[bidx * NNEG + jj - 1];
        if (c == 0) s_psc[t] = logit_scale[id];
        const float4* wrow4 = (const float4*)(W_out + (long)id * DD);
        const float4* xr4   = (const float4*)&s_xout[r][0];
        float dot = 0.0f, ss = 0.0f;
#pragma unroll
        for (int k2 = 0; k2 < 4; ++k2) {
            const int j = c + 8 * k2;
            float4 w4 = wrow4[j];
            float4 x4 = xr4[j];
            dot += w4.x * x4.x + w4.y * x4.y + w4.z * x4.z + w4.w * x4.w;
            ss  += w4.x * w4.x + w4.y * w4.y + w4.z * w4.z + w4.w * w4.w;
        }
        s_dp[t][c] = dot;
        s_sp[t][c] = ss;
    }
    __syncthreads();

    // ---- Phase 3b: per-task fold (fixed order) + log-sigmoid ----
    if (tid < NTASK) {
        const int t  = tid;
        const int jj = t % (1 + NNEG);
        float dot = s_dp[t][0], ss = s_sp[t][0];
#pragma unroll
        for (int c = 1; c < 8; ++c) { dot += s_dp[t][c]; ss += s_sp[t][c]; }
        const float logit = dot * rsqrtf(ss) * s_psc[t] * SQRT_D;
        const float z  = (jj == 0) ? logit : -logit;
        const float ls = fminf(z, 0.0f) - log1pf(__expf(-fabsf(z)));   // stable log_sigmoid
        s_ls[t] = (jj == 0) ? ls * (1.0f / BB) : ls * (1.0f / (BB * NNEG));
    }
    __syncthreads();
    if (tid == 0) {
        float tot = 0.0f;
#pragma unroll
        for (int t = 0; t < NTASK; ++t) tot += s_ls[t];
        atomicAdd(out, -tot);
    }
}

extern "C" void kernel_launch(void* const* d_in, const int* in_sizes, int n_in,
                              void* d_out, int out_size, void* d_ws, size_t ws_size,
                              hipStream_t stream) {
    (void)in_sizes; (void)n_in; (void)out_size; (void)ws_size;
    const int*   input_ids    = (const int*)  d_in[0];
    const int*   target_ids   = (const int*)  d_in[1];
    const int*   neg_ids      = (const int*)  d_in[2];
    const float* W_in         = (const float*)d_in[3];
    const float* W_out        = (const float*)d_in[4];
    const float* W_hidden     = (const float*)d_in[5];
    const float* W_gate       = (const float*)d_in[6];
    const float* W_ff_out     = (const float*)d_in[7];
    const float* hidden_scale = (const float*)d_in[8];
    const float* gate_scale   = (const float*)d_in[9];
    const float* logit_scale  = (const float*)d_in[10];
    float* out = (float*)d_out;
    float* ws  = (float*)d_ws;     // needs 270 KB

    prep_kernel<<<54, 256, 0, stream>>>(W_hidden, W_gate, W_ff_out,
                                        hidden_scale, gate_scale, ws, out);
    main_kernel<<<NBLK, NTHR, 0, stream>>>(input_ids, target_ids, neg_ids,
                                           W_in, W_out, logit_scale, ws, out);
}

// Round 12
// 148.384 us; speedup vs baseline: 1.0652x; 1.0010x over previous
//
#include <hip/hip_runtime.h>
#include <math.h>

#define DD    128
#define DI    170
#define DIP   176            // padded i-dimension (zero pad cols 170..175)
#define ND4   32             // DD/4 d-chunks
#define ND4H  16             // half of ND4 (split-d)
#define NI4P  44             // padded i4 chunk count (chunk 42 half, 43 zero)
#define BB    4096
#define NNEG  5
#define ROWS  8
#define NBLK  (BB / ROWS)    // 512 blocks -> ONE cohort: 2 blocks/CU resident
#define NTHR  512
#define NTASK (ROWS * (1 + NNEG))   // 48 gather tasks
#define XOP   132            // padded s_xout row stride (floats)
#define SQRT_D 11.3137084989847603904f   // sqrt(128)

// workspace layout (floats)
#define WS_WHT 0                          // [32][176] float4
#define WS_WGT (ND4 * DIP * 4)            // 22528 floats
#define WS_WFT (2 * ND4 * DIP * 4)        // 45056 floats; [44][128] float4

// async global->LDS, width 4: LDS dest = base + lane*4, global src per-lane
#define GLOAD_LDS4(gptr, lptr)                                                  \
    __builtin_amdgcn_global_load_lds(                                           \
        (const __attribute__((address_space(1))) void*)(gptr),                  \
        (__attribute__((address_space(3))) void*)(lptr), 4, 0, 0)

// barrier that orders LDS only: does NOT drain vmcnt, so in-flight
// global_load_lds DMA (waves 3/7's W_out prefetch) keeps flying.
#define BAR_LGKM() asm volatile("s_waitcnt lgkmcnt(0)\n\ts_barrier" ::: "memory")

__device__ __forceinline__ float wave_bcast_sum(float v) {
#pragma unroll
    for (int m = 1; m < 64; m <<= 1) v += __shfl_xor(v, m, 64);
    return v;
}

// Prep: per-call recompute of normalized+scale-folded TRANSPOSED weights into ws.
//  whT4[d4][i]  = W_hidden[i][4d4+c] * inv_h[i]*hidden_scale[i]*inv_f[i]
//  wgT4[d4][i]  = W_gate  [i][4d4+c] * inv_g[i]*gate_scale[i]*sqrt(D)
//  wfT4[i4][dd] = W_ff_out[dd][4i4+c]  (raw; col-norms folded via whT)
__global__ __launch_bounds__(256) void prep_kernel(
    const float* __restrict__ W_hidden,
    const float* __restrict__ W_gate,
    const float* __restrict__ W_ff_out,
    const float* __restrict__ hidden_scale,
    const float* __restrict__ gate_scale,
    float* __restrict__ ws,
    float* __restrict__ out)
{
    if (blockIdx.x == 0 && threadIdx.x == 0) out[0] = 0.0f;
    const int wave = threadIdx.x >> 6;
    const int lane = threadIdx.x & 63;
    const int t = blockIdx.x * 4 + wave;
    float* whT = ws + WS_WHT;
    float* wgT = ws + WS_WGT;
    float* wfT = ws + WS_WFT;

    if (t < DI) {
        const int v = t;
        // inverse norm of W_ff_out column v (128 entries, stride DI)
        float a = W_ff_out[(long)(2 * lane)     * DI + v];
        float b = W_ff_out[(long)(2 * lane + 1) * DI + v];
        float cf = wave_bcast_sum(a * a + b * b);
        // row norms of W_hidden / W_gate row v
        float2 ph = ((const float2*)(W_hidden + (long)v * DD))[lane];
        float2 pg = ((const float2*)(W_gate   + (long)v * DD))[lane];
        float sh = wave_bcast_sum(ph.x * ph.x + ph.y * ph.y);
        float sg = wave_bcast_sum(pg.x * pg.x + pg.y * pg.y);
        const float whs = rsqrtf(sh) * hidden_scale[v] * rsqrtf(cf);
        const float wgs = rsqrtf(sg) * gate_scale[v] * SQRT_D;
        // transposed write: lane holds d = 2*lane, 2*lane+1 -> d4 = lane>>1
        const int d4   = lane >> 1;
        const int half = lane & 1;                  // 0: comps {0,1}, 1: comps {2,3}
        float2* dh = (float2*)(whT + ((long)d4 * DIP + v) * 4 + half * 2);
        *dh = make_float2(ph.x * whs, ph.y * whs);
        float2* dg = (float2*)(wgT + ((long)d4 * DIP + v) * 4 + half * 2);
        *dg = make_float2(pg.x * wgs, pg.y * wgs);
    } else if (t < DI + NI4P) {
        const int i4 = t - DI;                      // 0..43
#pragma unroll
        for (int rr = 0; rr < 2; ++rr) {
            const int dd = rr * 64 + lane;
            float4 v4;
            if (i4 < 42) {   // rows are 8B-aligned (680B): use two float2 loads
                float2 lo = *(const float2*)(W_ff_out + (long)dd * DI + 4 * i4);
                float2 hi = *(const float2*)(W_ff_out + (long)dd * DI + 4 * i4 + 2);
                v4 = make_float4(lo.x, lo.y, hi.x, hi.y);
            } else if (i4 == 42) {  // i = 168,169 valid; 170,171 zero-pad
                float2 lo = *(const float2*)(W_ff_out + (long)dd * DI + 168);
                v4 = make_float4(lo.x, lo.y, 0.0f, 0.0f);
            } else {                // i4 == 43: all pad
                v4 = make_float4(0.0f, 0.0f, 0.0f, 0.0f);
            }
            *(float4*)(wfT + ((long)i4 * DD + dd) * 4) = v4;
        }
    } else if (t == DI + NI4P || t == DI + NI4P + 1) {
        // zero pad columns 170..175 of whT / wgT
        float* base = (t == DI + NI4P) ? whT : wgT;
        for (int idx = lane; idx < ND4 * 6; idx += 64) {
            const int d4 = idx / 6, c = idx % 6;
            *(float4*)(base + ((long)d4 * DIP + DI + c) * 4) =
                make_float4(0.0f, 0.0f, 0.0f, 0.0f);
        }
    }
}

__global__ __launch_bounds__(NTHR, 4) void main_kernel(
    const int*   __restrict__ input_ids,
    const int*   __restrict__ target_ids,
    const int*   __restrict__ neg_ids,
    const float* __restrict__ W_in,
    const float* __restrict__ W_out,
    const float* __restrict__ logit_scale,
    const float* __restrict__ ws,
    float* __restrict__ out)
{
    __shared__ __align__(16) float s_emb[ROWS][DD];    // 4 KB
    __shared__ __align__(16) float s_x[ROWS][DIP];     // 5.5 KB
    __shared__ __align__(16) float s_pp[4][ROWS][DD];  // 16 KB: 2b 4-slice partials
    __shared__ __align__(16) float s_xout[ROWS][XOP];  // 4.125 KB (132-pad)
    __shared__ __align__(16) float s_wout[NTASK][DD];  // 24 KB: prefetched W_out rows
    __shared__ float s_part[DIP][2 * ROWS + 1];        // [176][17]: split-d partials
    __shared__ float s_dp[NTASK][9];                   // P3 dot partials
    __shared__ float s_sp[NTASK][9];                   // P3 |w|^2 partials
    __shared__ float s_psc[NTASK];                     // logit_scale[id]
    __shared__ float s_ls[NTASK];                      // weighted log-sigmoid

    const int tid  = threadIdx.x;
    const int wave = tid >> 6;
    const int lane = tid & 63;
    const int b0   = blockIdx.x * ROWS;

    const float4* whT4 = (const float4*)(ws + WS_WHT);  // [32][176]
    const float4* wgT4 = (const float4*)(ws + WS_WGT);
    const float4* wfT4 = (const float4*)(ws + WS_WFT);  // [44][128]

    // ---- Phase 1: gather + l2-normalize input embeddings; wave w -> row w ----
    {
        const int id = input_ids[b0 + wave];
        float2 p = ((const float2*)(W_in + (long)id * DD))[lane];
        float s  = wave_bcast_sum(p.x * p.x + p.y * p.y);
        float inv = rsqrtf(s);
        s_emb[wave][2 * lane]     = p.x * inv;
        s_emb[wave][2 * lane + 1] = p.y * inv;
    }
    BAR_LGKM();    // orders s_emb only; no vmem to drain at this point

    // ---- Phase 2 (compute waves): FUSED h+g per thread, split-d:
    //      G_A (tid<176) d4 0..15, G_B (256..431) d4 16..31.
    //      CONCURRENTLY, waves 3 and 7 (idle in P2) run the whole phase-3
    //      gather chain: ids -> shfl broadcast -> global_load_lds of all 48
    //      W_out rows into s_wout + logit_scale into s_psc. Zero register
    //      cost for the rows; per-wave vmcnt ownership means no other
    //      wave's loads couple to these. lgkm-only barriers keep the DMA
    //      in flight until the full __syncthreads before P3a. ----
    const bool gA = (tid < DIP);
    const bool gB = (tid >= 256 && tid < 256 + DIP);
    const int i = gA ? tid : (gB ? tid - 256 : -1);
    float ah[ROWS], ag[ROWS];
#pragma unroll
    for (int r = 0; r < ROWS; ++r) { ah[r] = 0.0f; ag[r] = 0.0f; }

    if (i >= 0) {
        const int d4lo = gA ? 0 : ND4H;
#pragma unroll 4
        for (int k = 0; k < ND4H; ++k) {
            const int d4 = d4lo + k;
            float4 h4 = whT4[d4 * DIP + i];      // lane-consecutive: coalesced
            float4 g4 = wgT4[d4 * DIP + i];
#pragma unroll
            for (int r = 0; r < ROWS; ++r) {
                float4 e4 = ((const float4*)s_emb[r])[d4];   // uniform: broadcast
                ah[r] += e4.x * h4.x + e4.y * h4.y + e4.z * h4.z + e4.w * h4.w;
                ag[r] += e4.x * g4.x + e4.y * g4.y + e4.z * g4.z + e4.w * g4.w;
            }
        }
    } else if (wave == 3 || wave == 7) {
        const int tb = (wave == 3) ? 0 : 24;
        int   myid  = 0;
        float mypsc = 0.0f;
        if (lane < 24) {
            const int t  = tb + lane;
            const int r  = t / (1 + NNEG);
            const int jj = t % (1 + NNEG);
            const int bidx = b0 + r;
            myid  = (jj == 0) ? target_ids[bidx] : neg_ids[bidx * NNEG + jj - 1];
            mypsc = logit_scale[myid];           // dependent; issued before gathers
        }
#pragma unroll
        for (int k = 0; k < 24; ++k) {
            const int t   = tb + k;
            const int idt = __shfl(myid, k, 64); // broadcast task id to all lanes
            const float* gsrc = W_out + (long)idt * DD;
            GLOAD_LDS4(gsrc + lane,      &s_wout[t][0]);
            GLOAD_LDS4(gsrc + 64 + lane, &s_wout[t][64]);
        }
        if (lane < 24) s_psc[tb + lane] = mypsc;
    }
    if (gB) {
#pragma unroll
        for (int r = 0; r < ROWS; ++r) {
            s_part[i][r]        = ah[r];
            s_part[i][ROWS + r] = ag[r];
        }
    }
    BAR_LGKM();

    if (gA) {
#pragma unroll
        for (int r = 0; r < ROWS; ++r) {
            float h = ah[r] + s_part[i][r];           // (d4<16) + (d4>=16)
            float g = ag[r] + s_part[i][ROWS + r];
            float x = (g / (1.0f + __expf(-g))) * h;  // silu(g) * h
            s_x[r][i] = x;                            // pad cols: 0
        }
    }
    BAR_LGKM();

    // ---- Phase 2b: 4-slice split-i (q = tid>>7 owns i4 in [11q,11q+11)),
    //      thread (q,dd) accumulates all 8 rows; wfT streamed once/block. ----
    {
        const int dd = tid & 127;
        const int q  = tid >> 7;                  // 0..3
        const int i4lo = q * 11;
        float acc[ROWS];
#pragma unroll
        for (int r = 0; r < ROWS; ++r) acc[r] = 0.0f;
#pragma unroll 4
        for (int k = 0; k < 11; ++k) {
            const int i4 = i4lo + k;
            float4 w4 = wfT4[i4 * DD + dd];       // coalesced
#pragma unroll
            for (int r = 0; r < ROWS; ++r) {
                float4 x4 = ((const float4*)s_x[r])[i4];     // uniform: broadcast
                acc[r] += w4.x * x4.x + w4.y * x4.y + w4.z * x4.z + w4.w * x4.w;
            }
        }
#pragma unroll
        for (int r = 0; r < ROWS; ++r) s_pp[q][r][dd] = acc[r];
    }
    BAR_LGKM();

    // ---- materialize xout: fixed 4-term fold (deterministic) ----
    {
        const int dd = tid & 127;
        const int r0 = tid >> 7;                  // 0..3; rows r0, r0+4
#pragma unroll
        for (int rr = 0; rr < 2; ++rr) {
            const int r = r0 + 4 * rr;
            float v = ((s_pp[0][r][dd] + s_pp[1][r][dd])
                       + s_pp[2][r][dd]) + s_pp[3][r][dd];
            s_xout[r][dd] = v;
        }
    }
    // Full barrier: drains each wave's own vmcnt — waves 3/7's gathers are
    // long complete by now, so this is cheap; afterwards s_wout/s_psc are
    // visible to all waves.
    __syncthreads();

    // ---- Phase 3a: DATA-PARALLEL logits, all operands in LDS. 8 threads
    //      per task; thread c owns float4 chunks j = c + 8*k2. ----
    if (tid < NTASK * 8) {
        const int t  = tid >> 3;                  // 0..47
        const int c  = tid & 7;                   // 0..7
        const int r  = t / (1 + NNEG);
        const float4* wrow4 = (const float4*)&s_wout[t][0];
        const float4* xr4   = (const float4*)&s_xout[r][0];
        float dot = 0.0f, ss = 0.0f;
#pragma unroll
        for (int k2 = 0; k2 < 4; ++k2) {
            const int j = c + 8 * k2;
            float4 w4 = wrow4[j];
            float4 x4 = xr4[j];
            dot += w4.x * x4.x + w4.y * x4.y + w4.z * x4.z + w4.w * x4.w;
            ss  += w4.x * w4.x + w4.y * w4.y + w4.z * w4.z + w4.w * w4.w;
        }
        s_dp[t][c] = dot;
        s_sp[t][c] = ss;
    }
    __syncthreads();

    // ---- Phase 3b: per-task fold (fixed order) + log-sigmoid ----
    if (tid < NTASK) {
        const int t  = tid;
        const int jj = t % (1 + NNEG);
        float dot = s_dp[t][0], ss = s_sp[t][0];
#pragma unroll
        for (int c = 1; c < 8; ++c) { dot += s_dp[t][c]; ss += s_sp[t][c]; }
        const float logit = dot * rsqrtf(ss) * s_psc[t] * SQRT_D;
        const float z  = (jj == 0) ? logit : -logit;
        const float ls = fminf(z, 0.0f) - log1pf(__expf(-fabsf(z)));   // stable log_sigmoid
        s_ls[t] = (jj == 0) ? ls * (1.0f / BB) : ls * (1.0f / (BB * NNEG));
    }
    __syncthreads();
    if (tid == 0) {
        float tot = 0.0f;
#pragma unroll
        for (int t = 0; t < NTASK; ++t) tot += s_ls[t];
        atomicAdd(out, -tot);
    }
}

extern "C" void kernel_launch(void* const* d_in, const int* in_sizes, int n_in,
                              void* d_out, int out_size, void* d_ws, size_t ws_size,
                              hipStream_t stream) {
    (void)in_sizes; (void)n_in; (void)out_size; (void)ws_size;
    const int*   input_ids    = (const int*)  d_in[0];
    const int*   target_ids   = (const int*)  d_in[1];
    const int*   neg_ids      = (const int*)  d_in[2];
    const float* W_in         = (const float*)d_in[3];
    const float* W_out        = (const float*)d_in[4];
    const float* W_hidden     = (const float*)d_in[5];
    const float* W_gate       = (const float*)d_in[6];
    const float* W_ff_out     = (const float*)d_in[7];
    const float* hidden_scale = (const float*)d_in[8];
    const float* gate_scale   = (const float*)d_in[9];
    const float* logit_scale  = (const float*)d_in[10];
    float* out = (float*)d_out;
    float* ws  = (float*)d_ws;     // needs 270 KB

    prep_kernel<<<54, 256, 0, stream>>>(W_hidden, W_gate, W_ff_out,
                                        hidden_scale, gate_scale, ws, out);
    main_kernel<<<NBLK, NTHR, 0, stream>>>(input_ids, target_ids, neg_ids,
                                           W_in, W_out, logit_scale, ws, out);
}